// Round 12
// baseline (484.048 us; speedup 1.0000x reference)
//
#include <hip/hip_runtime.h>

#define B2 2
#define NQ 2048
#define NK 2048
#define DM 1024
#define NH 16
#define DK 64
#define KC 64

typedef unsigned short u16;
typedef __attribute__((ext_vector_type(8))) short bf16x8;
typedef __attribute__((ext_vector_type(4))) float f32x4;

__device__ __forceinline__ u16 f2bf(float f) {
  unsigned u = __float_as_uint(f);
  u += 0x7FFFu + ((u >> 16) & 1u);
  return (u16)(u >> 16);
}
__device__ __forceinline__ float bf2f(u16 u) {
  return __uint_as_float(((unsigned)u) << 16);
}
// load 8 fp32, round to bf16x8
__device__ __forceinline__ bf16x8 ld8f(const float* __restrict__ p) {
  const float4 a = *(const float4*)p;
  const float4 b = *(const float4*)(p + 4);
  bf16x8 v;
  v[0] = (short)f2bf(a.x); v[1] = (short)f2bf(a.y);
  v[2] = (short)f2bf(a.z); v[3] = (short)f2bf(a.w);
  v[4] = (short)f2bf(b.x); v[5] = (short)f2bf(b.y);
  v[6] = (short)f2bf(b.z); v[7] = (short)f2bf(b.w);
  return v;
}

#if __has_builtin(__builtin_amdgcn_exp2f)
#define EXP2F(x) __builtin_amdgcn_exp2f(x)
#else
#define EXP2F(x) exp2f(x)
#endif

#define MFMA(a, b, c) __builtin_amdgcn_mfma_f32_16x16x32_bf16(a, b, c, 0, 0, 0)

// exp(x*wgt/8) = exp2(x * (wgt*log2(e)/8)); the /8*log2e factor is FOLDED INTO fw
#define EXPC 0.18033688011112043f

// ------- shared 128x128 GEMM core: Y = A[M,1024] * W[N,1024]^T, fp32/bf16 sources -----
template <bool AF32, bool WF32>
__device__ __forceinline__ void gemm_core(
    const void* __restrict__ Ap, const void* __restrict__ Wp,
    int tm, int tn, u16* As, u16* Bs, f32x4 acc[4][4]) {
  const int tid = threadIdx.x;
  const int lane = tid & 63;
  const int wid = tid >> 6;
  const int wm = (wid >> 1) * 64, wn = (wid & 1) * 64;
  const int cc = lane & 15, gg = lane >> 4;
  const int srow = tid >> 2, scol = 8 * (tid & 3);
  const size_t ra0 = (size_t)(tm + srow) * DM + scol;
  const size_t ra1 = (size_t)(tm + 64 + srow) * DM + scol;
  const size_t rb0 = (size_t)(tn + srow) * DM + scol;
  const size_t rb1 = (size_t)(tn + 64 + srow) * DM + scol;
  const float* Af = (const float*)Ap; const u16* Ab = (const u16*)Ap;
  const float* Wf = (const float*)Wp; const u16* Wb = (const u16*)Wp;
  const f32x4 Z4 = {0.f, 0.f, 0.f, 0.f};
#pragma unroll
  for (int i = 0; i < 4; i++)
#pragma unroll
    for (int j = 0; j < 4; j++) acc[i][j] = Z4;

#define LD_A(off) (AF32 ? ld8f(Af + (off)) : *(const bf16x8*)(Ab + (off)))
#define LD_W(off) (WF32 ? ld8f(Wf + (off)) : *(const bf16x8*)(Wb + (off)))
  *(bf16x8*)&As[tid * 8]        = LD_A(ra0);
  *(bf16x8*)&As[2048 + tid * 8] = LD_A(ra1);
  *(bf16x8*)&Bs[tid * 8]        = LD_W(rb0);
  *(bf16x8*)&Bs[2048 + tid * 8] = LD_W(rb1);

  int buf = 0;
  for (int kk = 0; kk < DM; kk += 32) {
    __syncthreads();
    const int o = buf * 4096;
    bf16x8 af[4], bv[4];
#pragma unroll
    for (int i = 0; i < 4; i++) af[i] = *(const bf16x8*)&As[o + (wm + i * 16 + cc) * 32 + 8 * gg];
#pragma unroll
    for (int i = 0; i < 4; i++) bv[i] = *(const bf16x8*)&Bs[o + (wn + i * 16 + cc) * 32 + 8 * gg];
    if (kk + 32 < DM) {
      const int p = (buf ^ 1) * 4096;
      *(bf16x8*)&As[p + tid * 8]        = LD_A(ra0 + kk + 32);
      *(bf16x8*)&As[p + 2048 + tid * 8] = LD_A(ra1 + kk + 32);
      *(bf16x8*)&Bs[p + tid * 8]        = LD_W(rb0 + kk + 32);
      *(bf16x8*)&Bs[p + 2048 + tid * 8] = LD_W(rb1 + kk + 32);
    }
#pragma unroll
    for (int mi = 0; mi < 4; mi++)
#pragma unroll
      for (int ni = 0; ni < 4; ni++) acc[mi][ni] = MFMA(af[mi], bv[ni], acc[mi][ni]);
    buf ^= 1;
  }
#undef LD_A
#undef LD_W
}

// ---------------- K1: QKV projections + fw conversion (blocks >= 768) ------------------
__global__ __launch_bounds__(256) void k_proj(
    const float* __restrict__ xq, const float* __restrict__ xk, const float* __restrict__ xv,
    const float* __restrict__ wq, const float* __restrict__ wk, const float* __restrict__ wv,
    const float* __restrict__ bq, const float* __restrict__ bk, const float* __restrict__ bv,
    const float* __restrict__ qmask, const float* __restrict__ kmask,
    u16* __restrict__ q_ws, u16* __restrict__ k_ws, u16* __restrict__ vT_ws,
    const float* __restrict__ attw, const int* __restrict__ amask, u16* __restrict__ fwo) {
  const int bid = blockIdx.x;
  if (bid >= 768) {  // fw = amask ? NaN : bf16(attw*EXPC) — overlaps the GEMM blocks
    for (int i = ((bid - 768) * 256 + threadIdx.x) * 8; i < NQ * NK * B2;
         i += 1024 * 256 * 8) {
#pragma unroll
      for (int hh = 0; hh < 2; hh++) {
        const float4 w = *(const float4*)(attw + i + 4 * hh);
        const int4 m = *(const int4*)(amask + i + 4 * hh);
        ushort4 o;
        o.x = m.x ? 0x7FC0 : f2bf(w.x * EXPC);
        o.y = m.y ? 0x7FC0 : f2bf(w.y * EXPC);
        o.z = m.z ? 0x7FC0 : f2bf(w.z * EXPC);
        o.w = m.w ? 0x7FC0 : f2bf(w.w * EXPC);
        *(ushort4*)(fwo + i + 4 * hh) = o;
      }
    }
    return;
  }
  __shared__ u16 As[2 * 4096];
  __shared__ u16 Bs[2 * 4096];
  // bijective XCD swizzle: 768 = 8 x 96
  const int swz = (bid & 7) * 96 + (bid >> 3);
  const int tm = (swz & 31) * 128;
  const int yz = swz >> 5;               // 0..23
  const int tn = (yz & 7) * 128;
  const int z = yz >> 3;                 // 0..2
  const float* A = (z == 0) ? xq : (z == 1) ? xk : xv;
  const float* Wm = (z == 0) ? wq : (z == 1) ? wk : wv;
  const float* bias = (z == 0) ? bq : (z == 1) ? bk : bv;
  const float* rmask = (z == 0) ? qmask : kmask;
  f32x4 acc[4][4];
  gemm_core<true, true>(A, Wm, tm, tn, As, Bs, acc);

  const int lane = threadIdx.x & 63;
  const int wid = threadIdx.x >> 6;
  const int wm = (wid >> 1) * 64, wn = (wid & 1) * 64;
  const int cc = lane & 15, gg = lane >> 4;
  const int b = tm >> 11;
  const int tok0 = tm & 2047;
#pragma unroll
  for (int mi = 0; mi < 4; mi++) {
    const int rl = wm + mi * 16 + 4 * gg;
    float rm[4];
#pragma unroll
    for (int r = 0; r < 4; r++) rm[r] = rmask[b * NQ + tok0 + rl + r];
#pragma unroll
    for (int ni = 0; ni < 4; ni++) {
      const int col = tn + wn + ni * 16 + cc;
      const int h = col >> 6, d = col & 63;
      const float bs = bias[col];
      f32x4 a = acc[mi][ni];
      if (z <= 1) {
        u16* dst = ((z == 0) ? q_ws : k_ws) +
                   ((size_t)(b * NH + h) * NQ + tok0 + rl) * DK + d;
#pragma unroll
        for (int r = 0; r < 4; r++) dst[(size_t)r * DK] = f2bf((a[r] + bs) * rm[r]);
      } else {
        ushort4 pk;
        pk.x = f2bf((a[0] + bs) * rm[0]);
        pk.y = f2bf((a[1] + bs) * rm[1]);
        pk.z = f2bf((a[2] + bs) * rm[2]);
        pk.w = f2bf((a[3] + bs) * rm[3]);
        *(ushort4*)(vT_ws + ((size_t)(b * NH + h) * DK + d) * NK + tok0 + rl) = pk;
      }
    }
  }
}

// ---------------- K2: softmax-sum + att write + PV; 128 q-rows, 2 q-groups/wave -------
// grid (16,32): XCD = qb_idx%8 -> per-XCD fw working set 2 MB (L2-fit), all heads share
__global__ __launch_bounds__(256) void k_attn(
    const u16* __restrict__ q_ws, const u16* __restrict__ k_ws, const u16* __restrict__ vT_ws,
    const u16* __restrict__ fw, float* __restrict__ att_out, u16* __restrict__ ctxb) {
  __shared__ u16 Ks[128][72];         // loop1: 128 K rows; loop2: K rows 0..63, V rows 64..127
  __shared__ u16 Ps[4][16][72];
  const int bh = blockIdx.y;
  const int b = bh >> 4, hh = bh & 15;
  const int qb = blockIdx.x * 128;
  const int tid = threadIdx.x, lane = tid & 63, wid = tid >> 6;
  const int cc = lane & 15, gg = lane >> 4;
  const f32x4 Z4 = {0.f, 0.f, 0.f, 0.f};
  const int sr = tid >> 3, sc = 8 * (tid & 7);

  int qr[2];
  qr[0] = qb + wid * 16;
  qr[1] = qb + 64 + wid * 16;
  bf16x8 aq0[2], aq1[2];
  const u16* fwrow[2];
  float* attrow[2];
#pragma unroll
  for (int g = 0; g < 2; g++) {
    const u16* qp = q_ws + ((size_t)bh * NQ + qr[g] + cc) * DK + 8 * gg;
    aq0[g] = *(const bf16x8*)qp;
    aq1[g] = *(const bf16x8*)(qp + 32);
    fwrow[g] = fw + ((size_t)b * NQ + qr[g] + cc) * NK;
    attrow[g] = att_out + (size_t)bh * NQ * NK + (size_t)(qr[g] + cc) * NK;
  }

  // ---- loop1: denominators for both q-groups ----
  float sum[2] = {0.f, 0.f};
  for (int kc = 0; kc < NK; kc += 128) {
#pragma unroll
    for (int i = 0; i < 4; i++)
      *(bf16x8*)&Ks[i * 32 + sr][sc] =
          *(const bf16x8*)(k_ws + ((size_t)bh * NK + kc + i * 32 + sr) * DK + sc);
    __syncthreads();
#pragma unroll
    for (int n = 0; n < 8; n++) {
      const bf16x8 k0 = *(const bf16x8*)&Ks[n * 16 + cc][8 * gg];
      const bf16x8 k1 = *(const bf16x8*)&Ks[n * 16 + cc][32 + 8 * gg];
#pragma unroll
      for (int g = 0; g < 2; g++) {
        f32x4 acc = Z4;
        acc = MFMA(k0, aq0[g], acc);
        acc = MFMA(k1, aq1[g], acc);
        const ushort4 fv = *(const ushort4*)(fwrow[g] + kc + n * 16 + 4 * gg);
        const float e0 = EXP2F(acc[0] * bf2f(fv.x));
        const float e1 = EXP2F(acc[1] * bf2f(fv.y));
        const float e2 = EXP2F(acc[2] * bf2f(fv.z));
        const float e3 = EXP2F(acc[3] * bf2f(fv.w));
        sum[g] += (e0 == e0) ? e0 : 0.f;   // NaN w (masked) -> contributes 0
        sum[g] += (e1 == e1) ? e1 : 0.f;
        sum[g] += (e2 == e2) ? e2 : 0.f;
        sum[g] += (e3 == e3) ? e3 : 0.f;
      }
    }
    __syncthreads();
  }
  float rinv[2];
#pragma unroll
  for (int g = 0; g < 2; g++) {
    float s = sum[g];
    s += __shfl_xor(s, 16);
    s += __shfl_xor(s, 32);             // butterfly: every lane holds the full row sum
    rinv[g] = (s > 0.f) ? 1.0f / s : 0.f;
  }

  // ---- loop2: normalize, write att, PV (group-sequential per staged tile) ----
  f32x4 o[2][4];
#pragma unroll
  for (int g = 0; g < 2; g++)
#pragma unroll
    for (int i = 0; i < 4; i++) o[g][i] = Z4;

  for (int kc = 0; kc < NK; kc += KC) {
#pragma unroll
    for (int i = 0; i < 2; i++) {
      *(bf16x8*)&Ks[i * 32 + sr][sc] =
          *(const bf16x8*)(k_ws + ((size_t)bh * NK + kc + i * 32 + sr) * DK + sc);
      *(bf16x8*)&Ks[64 + i * 32 + sr][sc] =                 // V tile in rows 64..127
          *(const bf16x8*)(vT_ws + ((size_t)bh * DK + i * 32 + sr) * NK + kc + sc);
    }
    __syncthreads();
#pragma unroll
    for (int g = 0; g < 2; g++) {
      // QK^T swapped: p[q=cc][k=16n+4gg+r]
#pragma unroll
      for (int n = 0; n < 4; n++) {
        const bf16x8 k0 = *(const bf16x8*)&Ks[n * 16 + cc][8 * gg];
        const bf16x8 k1 = *(const bf16x8*)&Ks[n * 16 + cc][32 + 8 * gg];
        f32x4 acc = Z4;
        acc = MFMA(k0, aq0[g], acc);
        acc = MFMA(k1, aq1[g], acc);
        const int k0i = kc + n * 16 + 4 * gg;
        const ushort4 fv = *(const ushort4*)(fwrow[g] + k0i);
        const float e0 = EXP2F(acc[0] * bf2f(fv.x));
        const float e1 = EXP2F(acc[1] * bf2f(fv.y));
        const float e2 = EXP2F(acc[2] * bf2f(fv.z));
        const float e3 = EXP2F(acc[3] * bf2f(fv.w));
        f32x4 pv;
        pv.x = (e0 == e0) ? e0 * rinv[g] : 0.f;
        pv.y = (e1 == e1) ? e1 * rinv[g] : 0.f;
        pv.z = (e2 == e2) ? e2 * rinv[g] : 0.f;
        pv.w = (e3 == e3) ? e3 * rinv[g] : 0.f;
        __builtin_nontemporal_store(pv, (f32x4*)(attrow[g] + k0i));
        ushort4 pk;
        pk.x = f2bf(pv.x); pk.y = f2bf(pv.y); pk.z = f2bf(pv.z); pk.w = f2bf(pv.w);
        *(ushort4*)&Ps[wid][cc][n * 16 + 4 * gg] = pk;  // per-wave buffer; in-order reuse
      }
      // PV: O[16q x 64d] += P[16q x 64k] * V[64k x 64d]
      const bf16x8 pa0 = *(const bf16x8*)&Ps[wid][cc][8 * gg];
      const bf16x8 pa1 = *(const bf16x8*)&Ps[wid][cc][32 + 8 * gg];
#pragma unroll
      for (int nd = 0; nd < 4; nd++) {
        const bf16x8 vb0 = *(const bf16x8*)&Ks[64 + nd * 16 + cc][8 * gg];
        const bf16x8 vb1 = *(const bf16x8*)&Ks[64 + nd * 16 + cc][32 + 8 * gg];
        o[g][nd] = MFMA(pa0, vb0, o[g][nd]);
        o[g][nd] = MFMA(pa1, vb1, o[g][nd]);
      }
    }
    __syncthreads();
  }
  // PV C-layout: O[q=4gg+r][d=nd*16+cc]
#pragma unroll
  for (int g = 0; g < 2; g++)
#pragma unroll
    for (int nd = 0; nd < 4; nd++)
#pragma unroll
      for (int r = 0; r < 4; r++)
        ctxb[((size_t)b * NQ + qr[g] + 4 * gg + r) * DM + hh * 64 + nd * 16 + cc] =
            f2bf(o[g][nd][r]);
}

// ---------------- K3: out_final = ctx @ Wo^T + bo (bf16 ctx, fp32 Wo in-stage) --------
__global__ __launch_bounds__(256) void k_oproj(
    const u16* __restrict__ ctxb, const float* __restrict__ wo,
    const float* __restrict__ bo, float* __restrict__ outp) {
  __shared__ u16 As[2 * 4096];
  __shared__ u16 Bs[2 * 4096];
  const int bid = blockIdx.x;
  const int swz = ((bid & 7) << 5) + (bid >> 3);
  const int tm = (swz & 31) * 128;
  const int tn = (swz >> 5) * 128;
  f32x4 acc[4][4];
  gemm_core<false, true>(ctxb, wo, tm, tn, As, Bs, acc);
  const int lane = threadIdx.x & 63;
  const int wid = threadIdx.x >> 6;
  const int wm = (wid >> 1) * 64, wn = (wid & 1) * 64;
  const int cc = lane & 15, gg = lane >> 4;
#pragma unroll
  for (int mi = 0; mi < 4; mi++) {
    const int rl = tm + wm + mi * 16 + 4 * gg;
#pragma unroll
    for (int ni = 0; ni < 4; ni++) {
      const int col = tn + wn + ni * 16 + cc;
      const float bs = bo[col];
      f32x4 a = acc[mi][ni];
#pragma unroll
      for (int r = 0; r < 4; r++) outp[(size_t)(rl + r) * DM + col] = a[r] + bs;
    }
  }
}

extern "C" void kernel_launch(void* const* d_in, const int* in_sizes, int n_in,
                              void* d_out, int out_size, void* d_ws, size_t ws_size,
                              hipStream_t stream) {
  (void)in_sizes; (void)n_in; (void)out_size; (void)ws_size;
  const float* queries = (const float*)d_in[0];
  const float* keys    = (const float*)d_in[1];
  const float* values  = (const float*)d_in[2];
  const float* qmask   = (const float*)d_in[3];
  const float* kmask   = (const float*)d_in[4];
  const int*   amask   = (const int*)d_in[5];   // bool -> int32 on device
  const float* attw    = (const float*)d_in[6];
  const float* Wq = (const float*)d_in[7];
  const float* Wk = (const float*)d_in[8];
  const float* Wv = (const float*)d_in[9];
  const float* Wo = (const float*)d_in[10];
  const float* bq = (const float*)d_in[11];
  const float* bk = (const float*)d_in[12];
  const float* bv = (const float*)d_in[13];
  const float* bo = (const float*)d_in[14];

  float* outf = (float*)d_out;
  float* att_out = outf + (size_t)4194304;

  // persistent scratch in d_ws: 50.3 MiB
  char* p = (char*)d_ws;
  u16* q_ws  = (u16*)p; p += (size_t)4194304 * 2;
  u16* k_ws  = (u16*)p; p += (size_t)4194304 * 2;
  u16* vT_ws = (u16*)p; p += (size_t)4194304 * 2;
  u16* ctxb  = (u16*)p; p += (size_t)4194304 * 2;
  u16* fw    = (u16*)p; p += (size_t)8388608 * 2;  // fused mask+weight (pre-scaled by EXPC)

  k_proj<<<dim3(1792, 1, 1), 256, 0, stream>>>(queries, keys, values, Wq, Wk, Wv,
                                               bq, bk, bv, qmask, kmask,
                                               q_ws, k_ws, vT_ws, attw, amask, fw);
  k_attn<<<dim3(16, 32, 1), 256, 0, stream>>>(q_ws, k_ws, vT_ws, fw, att_out, ctxb);
  k_oproj<<<dim3(256, 1, 1), 256, 0, stream>>>(ctxb, Wo, bo, outf);
}

// Round 13
// 361.763 us; speedup vs baseline: 1.3380x; 1.3380x over previous
//
#include <hip/hip_runtime.h>

#define B2 2
#define NQ 2048
#define NK 2048
#define DM 1024
#define NH 16
#define DK 64
#define KC 64

typedef unsigned short u16;
typedef __attribute__((ext_vector_type(8))) short bf16x8;
typedef __attribute__((ext_vector_type(4))) float f32x4;

__device__ __forceinline__ u16 f2bf(float f) {
  unsigned u = __float_as_uint(f);
  u += 0x7FFFu + ((u >> 16) & 1u);
  return (u16)(u >> 16);
}
__device__ __forceinline__ float bf2f(u16 u) {
  return __uint_as_float(((unsigned)u) << 16);
}
// load 8 fp32, round to bf16x8
__device__ __forceinline__ bf16x8 ld8f(const float* __restrict__ p) {
  const float4 a = *(const float4*)p;
  const float4 b = *(const float4*)(p + 4);
  bf16x8 v;
  v[0] = (short)f2bf(a.x); v[1] = (short)f2bf(a.y);
  v[2] = (short)f2bf(a.z); v[3] = (short)f2bf(a.w);
  v[4] = (short)f2bf(b.x); v[5] = (short)f2bf(b.y);
  v[6] = (short)f2bf(b.z); v[7] = (short)f2bf(b.w);
  return v;
}

#if __has_builtin(__builtin_amdgcn_exp2f)
#define EXP2F(x) __builtin_amdgcn_exp2f(x)
#else
#define EXP2F(x) exp2f(x)
#endif

#define MFMA(a, b, c) __builtin_amdgcn_mfma_f32_16x16x32_bf16(a, b, c, 0, 0, 0)

// exp(x*wgt/8) = exp2(x * (wgt*log2(e)/8)); the /8*log2e factor is FOLDED INTO fw
#define EXPC 0.18033688011112043f

// ------- shared 128x128 GEMM core: Y = A[M,1024] * W[N,1024]^T, fp32/bf16 sources -----
template <bool AF32, bool WF32>
__device__ __forceinline__ void gemm_core(
    const void* __restrict__ Ap, const void* __restrict__ Wp,
    int tm, int tn, u16* As, u16* Bs, f32x4 acc[4][4]) {
  const int tid = threadIdx.x;
  const int lane = tid & 63;
  const int wid = tid >> 6;
  const int wm = (wid >> 1) * 64, wn = (wid & 1) * 64;
  const int cc = lane & 15, gg = lane >> 4;
  const int srow = tid >> 2, scol = 8 * (tid & 3);
  const size_t ra0 = (size_t)(tm + srow) * DM + scol;
  const size_t ra1 = (size_t)(tm + 64 + srow) * DM + scol;
  const size_t rb0 = (size_t)(tn + srow) * DM + scol;
  const size_t rb1 = (size_t)(tn + 64 + srow) * DM + scol;
  const float* Af = (const float*)Ap; const u16* Ab = (const u16*)Ap;
  const float* Wf = (const float*)Wp; const u16* Wb = (const u16*)Wp;
  const f32x4 Z4 = {0.f, 0.f, 0.f, 0.f};
#pragma unroll
  for (int i = 0; i < 4; i++)
#pragma unroll
    for (int j = 0; j < 4; j++) acc[i][j] = Z4;

#define LD_A(off) (AF32 ? ld8f(Af + (off)) : *(const bf16x8*)(Ab + (off)))
#define LD_W(off) (WF32 ? ld8f(Wf + (off)) : *(const bf16x8*)(Wb + (off)))
  *(bf16x8*)&As[tid * 8]        = LD_A(ra0);
  *(bf16x8*)&As[2048 + tid * 8] = LD_A(ra1);
  *(bf16x8*)&Bs[tid * 8]        = LD_W(rb0);
  *(bf16x8*)&Bs[2048 + tid * 8] = LD_W(rb1);

  int buf = 0;
  for (int kk = 0; kk < DM; kk += 32) {
    __syncthreads();
    const int o = buf * 4096;
    bf16x8 af[4], bv[4];
#pragma unroll
    for (int i = 0; i < 4; i++) af[i] = *(const bf16x8*)&As[o + (wm + i * 16 + cc) * 32 + 8 * gg];
#pragma unroll
    for (int i = 0; i < 4; i++) bv[i] = *(const bf16x8*)&Bs[o + (wn + i * 16 + cc) * 32 + 8 * gg];
    if (kk + 32 < DM) {
      const int p = (buf ^ 1) * 4096;
      *(bf16x8*)&As[p + tid * 8]        = LD_A(ra0 + kk + 32);
      *(bf16x8*)&As[p + 2048 + tid * 8] = LD_A(ra1 + kk + 32);
      *(bf16x8*)&Bs[p + tid * 8]        = LD_W(rb0 + kk + 32);
      *(bf16x8*)&Bs[p + 2048 + tid * 8] = LD_W(rb1 + kk + 32);
    }
#pragma unroll
    for (int mi = 0; mi < 4; mi++)
#pragma unroll
      for (int ni = 0; ni < 4; ni++) acc[mi][ni] = MFMA(af[mi], bv[ni], acc[mi][ni]);
    buf ^= 1;
  }
#undef LD_A
#undef LD_W
}

// ---------------- K1: QKV projections + fw conversion (blocks >= 768) ------------------
__global__ __launch_bounds__(256) void k_proj(
    const float* __restrict__ xq, const float* __restrict__ xk, const float* __restrict__ xv,
    const float* __restrict__ wq, const float* __restrict__ wk, const float* __restrict__ wv,
    const float* __restrict__ bq, const float* __restrict__ bk, const float* __restrict__ bv,
    const float* __restrict__ qmask, const float* __restrict__ kmask,
    u16* __restrict__ q_ws, u16* __restrict__ k_ws, u16* __restrict__ vT_ws,
    const float* __restrict__ attw, const int* __restrict__ amask, u16* __restrict__ fwo) {
  const int bid = blockIdx.x;
  if (bid >= 768) {  // fw = amask ? NaN : bf16(attw*EXPC) — overlaps the GEMM blocks
    for (int i = ((bid - 768) * 256 + threadIdx.x) * 8; i < NQ * NK * B2;
         i += 1024 * 256 * 8) {
#pragma unroll
      for (int hh = 0; hh < 2; hh++) {
        const float4 w = *(const float4*)(attw + i + 4 * hh);
        const int4 m = *(const int4*)(amask + i + 4 * hh);
        ushort4 o;
        o.x = m.x ? 0x7FC0 : f2bf(w.x * EXPC);
        o.y = m.y ? 0x7FC0 : f2bf(w.y * EXPC);
        o.z = m.z ? 0x7FC0 : f2bf(w.z * EXPC);
        o.w = m.w ? 0x7FC0 : f2bf(w.w * EXPC);
        *(ushort4*)(fwo + i + 4 * hh) = o;
      }
    }
    return;
  }
  __shared__ u16 As[2 * 4096];
  __shared__ u16 Bs[2 * 4096];
  // bijective XCD swizzle: 768 = 8 x 96
  const int swz = (bid & 7) * 96 + (bid >> 3);
  const int tm = (swz & 31) * 128;
  const int yz = swz >> 5;               // 0..23
  const int tn = (yz & 7) * 128;
  const int z = yz >> 3;                 // 0..2
  const float* A = (z == 0) ? xq : (z == 1) ? xk : xv;
  const float* Wm = (z == 0) ? wq : (z == 1) ? wk : wv;
  const float* bias = (z == 0) ? bq : (z == 1) ? bk : bv;
  const float* rmask = (z == 0) ? qmask : kmask;
  f32x4 acc[4][4];
  gemm_core<true, true>(A, Wm, tm, tn, As, Bs, acc);

  const int lane = threadIdx.x & 63;
  const int wid = threadIdx.x >> 6;
  const int wm = (wid >> 1) * 64, wn = (wid & 1) * 64;
  const int cc = lane & 15, gg = lane >> 4;
  const int b = tm >> 11;
  const int tok0 = tm & 2047;
#pragma unroll
  for (int mi = 0; mi < 4; mi++) {
    const int rl = wm + mi * 16 + 4 * gg;
    float rm[4];
#pragma unroll
    for (int r = 0; r < 4; r++) rm[r] = rmask[b * NQ + tok0 + rl + r];
#pragma unroll
    for (int ni = 0; ni < 4; ni++) {
      const int col = tn + wn + ni * 16 + cc;
      const int h = col >> 6, d = col & 63;
      const float bs = bias[col];
      f32x4 a = acc[mi][ni];
      if (z <= 1) {
        u16* dst = ((z == 0) ? q_ws : k_ws) +
                   ((size_t)(b * NH + h) * NQ + tok0 + rl) * DK + d;
#pragma unroll
        for (int r = 0; r < 4; r++) dst[(size_t)r * DK] = f2bf((a[r] + bs) * rm[r]);
      } else {
        ushort4 pk;
        pk.x = f2bf((a[0] + bs) * rm[0]);
        pk.y = f2bf((a[1] + bs) * rm[1]);
        pk.z = f2bf((a[2] + bs) * rm[2]);
        pk.w = f2bf((a[3] + bs) * rm[3]);
        *(ushort4*)(vT_ws + ((size_t)(b * NH + h) * DK + d) * NK + tok0 + rl) = pk;
      }
    }
  }
}

// ---------------- K2: merged softmax-sum + att write + PV (R11 structure + T14) -------
// dim3(32,32), 256 thr: XCD = qb_idx%8; async-STAGE: next tile loads issue before work
__global__ __launch_bounds__(256) void k_attn(
    const u16* __restrict__ q_ws, const u16* __restrict__ k_ws, const u16* __restrict__ vT_ws,
    const u16* __restrict__ fw, float* __restrict__ att_out, u16* __restrict__ ctxb) {
  __shared__ u16 Ks[128][72];         // loop1: 128 K rows; loop2: K rows 0..63, V rows 64..127
  __shared__ u16 Ps[4][16][72];
  const int bh = blockIdx.y;
  const int b = bh >> 4, hh = bh & 15;
  const int qb = blockIdx.x * 64;
  const int tid = threadIdx.x, lane = tid & 63, wid = tid >> 6;
  const int cc = lane & 15, gg = lane >> 4;
  const int qr0 = qb + wid * 16;
  const u16* qp = q_ws + ((size_t)bh * NQ + qr0 + cc) * DK + 8 * gg;
  const bf16x8 aq0 = *(const bf16x8*)qp;
  const bf16x8 aq1 = *(const bf16x8*)(qp + 32);
  const u16* fwrow = fw + ((size_t)b * NQ + qr0 + cc) * NK;
  const f32x4 Z4 = {0.f, 0.f, 0.f, 0.f};
  const int sr = tid >> 3, sc = 8 * (tid & 7);
  const u16* kb = k_ws + (size_t)bh * NK * DK;
  const u16* vb = vT_ws + (size_t)bh * DK * NK;

  // ---- loop1: denominators (T14: next-tile loads issued before compute) ----
  float sum = 0.f;
  bf16x8 st[4];
#pragma unroll
  for (int i = 0; i < 4; i++) st[i] = *(const bf16x8*)(kb + (size_t)(i * 32 + sr) * DK + sc);
#pragma unroll
  for (int i = 0; i < 4; i++) *(bf16x8*)&Ks[i * 32 + sr][sc] = st[i];
  for (int kc = 0; kc < NK; kc += 128) {
    __syncthreads();
    const bool more = (kc + 128) < NK;
    if (more) {
#pragma unroll
      for (int i = 0; i < 4; i++)
        st[i] = *(const bf16x8*)(kb + (size_t)(kc + 128 + i * 32 + sr) * DK + sc);
    }
#pragma unroll
    for (int n = 0; n < 8; n++) {
      const bf16x8 k0 = *(const bf16x8*)&Ks[n * 16 + cc][8 * gg];
      const bf16x8 k1 = *(const bf16x8*)&Ks[n * 16 + cc][32 + 8 * gg];
      f32x4 acc = Z4;
      acc = MFMA(k0, aq0, acc);
      acc = MFMA(k1, aq1, acc);
      const ushort4 fv = *(const ushort4*)(fwrow + kc + n * 16 + 4 * gg);
      const float e0 = EXP2F(acc[0] * bf2f(fv.x));
      const float e1 = EXP2F(acc[1] * bf2f(fv.y));
      const float e2 = EXP2F(acc[2] * bf2f(fv.z));
      const float e3 = EXP2F(acc[3] * bf2f(fv.w));
      sum += (e0 == e0) ? e0 : 0.f;   // NaN w (masked) -> contributes 0
      sum += (e1 == e1) ? e1 : 0.f;
      sum += (e2 == e2) ? e2 : 0.f;
      sum += (e3 == e3) ? e3 : 0.f;
    }
    __syncthreads();
    if (more) {
#pragma unroll
      for (int i = 0; i < 4; i++) *(bf16x8*)&Ks[i * 32 + sr][sc] = st[i];
    }
  }
  sum += __shfl_xor(sum, 16);
  sum += __shfl_xor(sum, 32);         // butterfly: every lane holds the full row sum
  // fold 1/sum into the exponent: p = exp2(acc*fv + lg2r)
  const float lg2r = (sum > 0.f) ? -__log2f(sum) : -__builtin_inff();

  // ---- loop2: normalize, write att, PV (T14 staged) ----
  f32x4 o[4];
#pragma unroll
  for (int i = 0; i < 4; i++) o[i] = Z4;
  float* attrow = att_out + (size_t)bh * NQ * NK + (size_t)(qr0 + cc) * NK;

  bf16x8 stk[2], stv[2];
#pragma unroll
  for (int i = 0; i < 2; i++) {
    stk[i] = *(const bf16x8*)(kb + (size_t)(i * 32 + sr) * DK + sc);
    stv[i] = *(const bf16x8*)(vb + (size_t)(i * 32 + sr) * NK + sc);
  }
#pragma unroll
  for (int i = 0; i < 2; i++) {
    *(bf16x8*)&Ks[i * 32 + sr][sc] = stk[i];
    *(bf16x8*)&Ks[64 + i * 32 + sr][sc] = stv[i];          // V tile in rows 64..127
  }
  for (int kc = 0; kc < NK; kc += KC) {
    __syncthreads();
    const bool more = (kc + KC) < NK;
    if (more) {
#pragma unroll
      for (int i = 0; i < 2; i++) {
        stk[i] = *(const bf16x8*)(kb + (size_t)(kc + KC + i * 32 + sr) * DK + sc);
        stv[i] = *(const bf16x8*)(vb + (size_t)(i * 32 + sr) * NK + kc + KC + sc);
      }
    }
    // QK^T swapped: p[q=cc][k=16n+4gg+r]
#pragma unroll
    for (int n = 0; n < 4; n++) {
      const bf16x8 k0 = *(const bf16x8*)&Ks[n * 16 + cc][8 * gg];
      const bf16x8 k1 = *(const bf16x8*)&Ks[n * 16 + cc][32 + 8 * gg];
      f32x4 acc = Z4;
      acc = MFMA(k0, aq0, acc);
      acc = MFMA(k1, aq1, acc);
      const int k0i = kc + n * 16 + 4 * gg;
      const ushort4 fv = *(const ushort4*)(fwrow + k0i);
      const float e0 = EXP2F(fmaf(acc[0], bf2f(fv.x), lg2r));
      const float e1 = EXP2F(fmaf(acc[1], bf2f(fv.y), lg2r));
      const float e2 = EXP2F(fmaf(acc[2], bf2f(fv.z), lg2r));
      const float e3 = EXP2F(fmaf(acc[3], bf2f(fv.w), lg2r));
      f32x4 pv;
      pv.x = (e0 == e0) ? e0 : 0.f;
      pv.y = (e1 == e1) ? e1 : 0.f;
      pv.z = (e2 == e2) ? e2 : 0.f;
      pv.w = (e3 == e3) ? e3 : 0.f;
      __builtin_nontemporal_store(pv, (f32x4*)(attrow + k0i));
      ushort4 pk;
      pk.x = f2bf(pv.x); pk.y = f2bf(pv.y); pk.z = f2bf(pv.z); pk.w = f2bf(pv.w);
      *(ushort4*)&Ps[wid][cc][n * 16 + 4 * gg] = pk;  // per-wave buffer: no barrier needed
    }
    // PV: O[16q x 64d] += P[16q x 64k] * V[64k x 64d]
    const bf16x8 pa0 = *(const bf16x8*)&Ps[wid][cc][8 * gg];
    const bf16x8 pa1 = *(const bf16x8*)&Ps[wid][cc][32 + 8 * gg];
#pragma unroll
    for (int nd = 0; nd < 4; nd++) {
      const bf16x8 vb0 = *(const bf16x8*)&Ks[64 + nd * 16 + cc][8 * gg];
      const bf16x8 vb1 = *(const bf16x8*)&Ks[64 + nd * 16 + cc][32 + 8 * gg];
      o[nd] = MFMA(pa0, vb0, o[nd]);
      o[nd] = MFMA(pa1, vb1, o[nd]);
    }
    __syncthreads();
    if (more) {
#pragma unroll
      for (int i = 0; i < 2; i++) {
        *(bf16x8*)&Ks[i * 32 + sr][sc] = stk[i];
        *(bf16x8*)&Ks[64 + i * 32 + sr][sc] = stv[i];
      }
    }
  }
  // PV C-layout: O[q=4gg+r][d=nd*16+cc]
#pragma unroll
  for (int nd = 0; nd < 4; nd++)
#pragma unroll
    for (int r = 0; r < 4; r++)
      ctxb[((size_t)b * NQ + qr0 + 4 * gg + r) * DM + hh * 64 + nd * 16 + cc] = f2bf(o[nd][r]);
}

// ---------------- K3: out_final = ctx @ Wo^T + bo (bf16 ctx, fp32 Wo in-stage) --------
__global__ __launch_bounds__(256) void k_oproj(
    const u16* __restrict__ ctxb, const float* __restrict__ wo,
    const float* __restrict__ bo, float* __restrict__ outp) {
  __shared__ u16 As[2 * 4096];
  __shared__ u16 Bs[2 * 4096];
  const int bid = blockIdx.x;
  const int swz = ((bid & 7) << 5) + (bid >> 3);
  const int tm = (swz & 31) * 128;
  const int tn = (swz >> 5) * 128;
  f32x4 acc[4][4];
  gemm_core<false, true>(ctxb, wo, tm, tn, As, Bs, acc);
  const int lane = threadIdx.x & 63;
  const int wid = threadIdx.x >> 6;
  const int wm = (wid >> 1) * 64, wn = (wid & 1) * 64;
  const int cc = lane & 15, gg = lane >> 4;
#pragma unroll
  for (int mi = 0; mi < 4; mi++) {
    const int rl = tm + wm + mi * 16 + 4 * gg;
#pragma unroll
    for (int ni = 0; ni < 4; ni++) {
      const int col = tn + wn + ni * 16 + cc;
      const float bs = bo[col];
      f32x4 a = acc[mi][ni];
#pragma unroll
      for (int r = 0; r < 4; r++) outp[(size_t)(rl + r) * DM + col] = a[r] + bs;
    }
  }
}

extern "C" void kernel_launch(void* const* d_in, const int* in_sizes, int n_in,
                              void* d_out, int out_size, void* d_ws, size_t ws_size,
                              hipStream_t stream) {
  (void)in_sizes; (void)n_in; (void)out_size; (void)ws_size;
  const float* queries = (const float*)d_in[0];
  const float* keys    = (const float*)d_in[1];
  const float* values  = (const float*)d_in[2];
  const float* qmask   = (const float*)d_in[3];
  const float* kmask   = (const float*)d_in[4];
  const int*   amask   = (const int*)d_in[5];   // bool -> int32 on device
  const float* attw    = (const float*)d_in[6];
  const float* Wq = (const float*)d_in[7];
  const float* Wk = (const float*)d_in[8];
  const float* Wv = (const float*)d_in[9];
  const float* Wo = (const float*)d_in[10];
  const float* bq = (const float*)d_in[11];
  const float* bk = (const float*)d_in[12];
  const float* bv = (const float*)d_in[13];
  const float* bo = (const float*)d_in[14];

  float* outf = (float*)d_out;
  float* att_out = outf + (size_t)4194304;

  // persistent scratch in d_ws: 50.3 MiB
  char* p = (char*)d_ws;
  u16* q_ws  = (u16*)p; p += (size_t)4194304 * 2;
  u16* k_ws  = (u16*)p; p += (size_t)4194304 * 2;
  u16* vT_ws = (u16*)p; p += (size_t)4194304 * 2;
  u16* ctxb  = (u16*)p; p += (size_t)4194304 * 2;
  u16* fw    = (u16*)p; p += (size_t)8388608 * 2;  // fused mask+weight (pre-scaled by EXPC)

  k_proj<<<dim3(1792, 1, 1), 256, 0, stream>>>(queries, keys, values, Wq, Wk, Wv,
                                               bq, bk, bv, qmask, kmask,
                                               q_ws, k_ws, vT_ws, attw, amask, fw);
  k_attn<<<dim3(32, 32, 1), 256, 0, stream>>>(q_ws, k_ws, vT_ws, fw, att_out, ctxb);
  k_oproj<<<dim3(256, 1, 1), 256, 0, stream>>>(ctxb, Wo, bo, outf);
}

// Round 14
// 333.398 us; speedup vs baseline: 1.4519x; 1.0851x over previous
//
#include <hip/hip_runtime.h>

#define B2 2
#define NQ 2048
#define NK 2048
#define DM 1024
#define NH 16
#define DK 64
#define KC 64

typedef unsigned short u16;
typedef __attribute__((ext_vector_type(8))) short bf16x8;
typedef __attribute__((ext_vector_type(4))) float f32x4;

__device__ __forceinline__ u16 f2bf(float f) {
  unsigned u = __float_as_uint(f);
  u += 0x7FFFu + ((u >> 16) & 1u);
  return (u16)(u >> 16);
}
__device__ __forceinline__ float bf2f(u16 u) {
  return __uint_as_float(((unsigned)u) << 16);
}
// load 8 fp32, round to bf16x8
__device__ __forceinline__ bf16x8 ld8f(const float* __restrict__ p) {
  const float4 a = *(const float4*)p;
  const float4 b = *(const float4*)(p + 4);
  bf16x8 v;
  v[0] = (short)f2bf(a.x); v[1] = (short)f2bf(a.y);
  v[2] = (short)f2bf(a.z); v[3] = (short)f2bf(a.w);
  v[4] = (short)f2bf(b.x); v[5] = (short)f2bf(b.y);
  v[6] = (short)f2bf(b.z); v[7] = (short)f2bf(b.w);
  return v;
}

#if __has_builtin(__builtin_amdgcn_exp2f)
#define EXP2F(x) __builtin_amdgcn_exp2f(x)
#else
#define EXP2F(x) exp2f(x)
#endif

#define MFMA(a, b, c) __builtin_amdgcn_mfma_f32_16x16x32_bf16(a, b, c, 0, 0, 0)

// exp(x*wgt/8) = exp2(x * (wgt*log2(e)/8)); the /8*log2e factor is FOLDED INTO fw
#define EXPC 0.18033688011112043f

// ------- shared 128x128 GEMM core: Y = A[M,1024] * W[N,1024]^T, fp32/bf16 sources -----
template <bool AF32, bool WF32>
__device__ __forceinline__ void gemm_core(
    const void* __restrict__ Ap, const void* __restrict__ Wp,
    int tm, int tn, u16* As, u16* Bs, f32x4 acc[4][4]) {
  const int tid = threadIdx.x;
  const int lane = tid & 63;
  const int wid = tid >> 6;
  const int wm = (wid >> 1) * 64, wn = (wid & 1) * 64;
  const int cc = lane & 15, gg = lane >> 4;
  const int srow = tid >> 2, scol = 8 * (tid & 3);
  const size_t ra0 = (size_t)(tm + srow) * DM + scol;
  const size_t ra1 = (size_t)(tm + 64 + srow) * DM + scol;
  const size_t rb0 = (size_t)(tn + srow) * DM + scol;
  const size_t rb1 = (size_t)(tn + 64 + srow) * DM + scol;
  const float* Af = (const float*)Ap; const u16* Ab = (const u16*)Ap;
  const float* Wf = (const float*)Wp; const u16* Wb = (const u16*)Wp;
  const f32x4 Z4 = {0.f, 0.f, 0.f, 0.f};
#pragma unroll
  for (int i = 0; i < 4; i++)
#pragma unroll
    for (int j = 0; j < 4; j++) acc[i][j] = Z4;

#define LD_A(off) (AF32 ? ld8f(Af + (off)) : *(const bf16x8*)(Ab + (off)))
#define LD_W(off) (WF32 ? ld8f(Wf + (off)) : *(const bf16x8*)(Wb + (off)))
  *(bf16x8*)&As[tid * 8]        = LD_A(ra0);
  *(bf16x8*)&As[2048 + tid * 8] = LD_A(ra1);
  *(bf16x8*)&Bs[tid * 8]        = LD_W(rb0);
  *(bf16x8*)&Bs[2048 + tid * 8] = LD_W(rb1);

  int buf = 0;
  for (int kk = 0; kk < DM; kk += 32) {
    __syncthreads();
    const int o = buf * 4096;
    bf16x8 af[4], bv[4];
#pragma unroll
    for (int i = 0; i < 4; i++) af[i] = *(const bf16x8*)&As[o + (wm + i * 16 + cc) * 32 + 8 * gg];
#pragma unroll
    for (int i = 0; i < 4; i++) bv[i] = *(const bf16x8*)&Bs[o + (wn + i * 16 + cc) * 32 + 8 * gg];
    if (kk + 32 < DM) {
      const int p = (buf ^ 1) * 4096;
      *(bf16x8*)&As[p + tid * 8]        = LD_A(ra0 + kk + 32);
      *(bf16x8*)&As[p + 2048 + tid * 8] = LD_A(ra1 + kk + 32);
      *(bf16x8*)&Bs[p + tid * 8]        = LD_W(rb0 + kk + 32);
      *(bf16x8*)&Bs[p + 2048 + tid * 8] = LD_W(rb1 + kk + 32);
    }
#pragma unroll
    for (int mi = 0; mi < 4; mi++)
#pragma unroll
      for (int ni = 0; ni < 4; ni++) acc[mi][ni] = MFMA(af[mi], bv[ni], acc[mi][ni]);
    buf ^= 1;
  }
#undef LD_A
#undef LD_W
}

// ---------------- K1: QKV projections + fw conversion (blocks >= 768) ------------------
__global__ __launch_bounds__(256) void k_proj(
    const float* __restrict__ xq, const float* __restrict__ xk, const float* __restrict__ xv,
    const float* __restrict__ wq, const float* __restrict__ wk, const float* __restrict__ wv,
    const float* __restrict__ bq, const float* __restrict__ bk, const float* __restrict__ bv,
    const float* __restrict__ qmask, const float* __restrict__ kmask,
    u16* __restrict__ q_ws, u16* __restrict__ k_ws, u16* __restrict__ vT_ws,
    const float* __restrict__ attw, const int* __restrict__ amask, u16* __restrict__ fwo) {
  const int bid = blockIdx.x;
  if (bid >= 768) {  // fw = amask ? NaN : bf16(attw*EXPC) — overlaps the GEMM blocks
    for (int i = ((bid - 768) * 256 + threadIdx.x) * 8; i < NQ * NK * B2;
         i += 1024 * 256 * 8) {
#pragma unroll
      for (int hh = 0; hh < 2; hh++) {
        const float4 w = *(const float4*)(attw + i + 4 * hh);
        const int4 m = *(const int4*)(amask + i + 4 * hh);
        ushort4 o;
        o.x = m.x ? 0x7FC0 : f2bf(w.x * EXPC);
        o.y = m.y ? 0x7FC0 : f2bf(w.y * EXPC);
        o.z = m.z ? 0x7FC0 : f2bf(w.z * EXPC);
        o.w = m.w ? 0x7FC0 : f2bf(w.w * EXPC);
        *(ushort4*)(fwo + i + 4 * hh) = o;
      }
    }
    return;
  }
  __shared__ u16 As[2 * 4096];
  __shared__ u16 Bs[2 * 4096];
  // bijective XCD swizzle: 768 = 8 x 96
  const int swz = (bid & 7) * 96 + (bid >> 3);
  const int tm = (swz & 31) * 128;
  const int yz = swz >> 5;               // 0..23
  const int tn = (yz & 7) * 128;
  const int z = yz >> 3;                 // 0..2
  const float* A = (z == 0) ? xq : (z == 1) ? xk : xv;
  const float* Wm = (z == 0) ? wq : (z == 1) ? wk : wv;
  const float* bias = (z == 0) ? bq : (z == 1) ? bk : bv;
  const float* rmask = (z == 0) ? qmask : kmask;
  f32x4 acc[4][4];
  gemm_core<true, true>(A, Wm, tm, tn, As, Bs, acc);

  const int lane = threadIdx.x & 63;
  const int wid = threadIdx.x >> 6;
  const int wm = (wid >> 1) * 64, wn = (wid & 1) * 64;
  const int cc = lane & 15, gg = lane >> 4;
  const int b = tm >> 11;
  const int tok0 = tm & 2047;
#pragma unroll
  for (int mi = 0; mi < 4; mi++) {
    const int rl = wm + mi * 16 + 4 * gg;
    float rm[4];
#pragma unroll
    for (int r = 0; r < 4; r++) rm[r] = rmask[b * NQ + tok0 + rl + r];
#pragma unroll
    for (int ni = 0; ni < 4; ni++) {
      const int col = tn + wn + ni * 16 + cc;
      const int h = col >> 6, d = col & 63;
      const float bs = bias[col];
      f32x4 a = acc[mi][ni];
      if (z <= 1) {
        u16* dst = ((z == 0) ? q_ws : k_ws) +
                   ((size_t)(b * NH + h) * NQ + tok0 + rl) * DK + d;
#pragma unroll
        for (int r = 0; r < 4; r++) dst[(size_t)r * DK] = f2bf((a[r] + bs) * rm[r]);
      } else {
        ushort4 pk;
        pk.x = f2bf((a[0] + bs) * rm[0]);
        pk.y = f2bf((a[1] + bs) * rm[1]);
        pk.z = f2bf((a[2] + bs) * rm[2]);
        pk.w = f2bf((a[3] + bs) * rm[3]);
        *(ushort4*)(vT_ws + ((size_t)(b * NH + h) * DK + d) * NK + tok0 + rl) = pk;
      }
    }
  }
}

// ---------------- K2: merged softmax-sum + att write + PV (R11-proven structure) ------
// dim3(32,32), 256 thr: XCD = qb_idx%8 -> fw slices L2-resident, reused by all heads
__global__ __launch_bounds__(256) void k_attn(
    const u16* __restrict__ q_ws, const u16* __restrict__ k_ws, const u16* __restrict__ vT_ws,
    const u16* __restrict__ fw, float* __restrict__ att_out, u16* __restrict__ ctxb) {
  __shared__ u16 Ks[128][72];         // loop1: 128 K rows; loop2: K rows 0..63, V rows 64..127
  __shared__ u16 Ps[4][16][72];
  const int bh = blockIdx.y;
  const int b = bh >> 4, hh = bh & 15;
  const int qb = blockIdx.x * 64;
  const int tid = threadIdx.x, lane = tid & 63, wid = tid >> 6;
  const int cc = lane & 15, gg = lane >> 4;
  const int qr0 = qb + wid * 16;
  const u16* qp = q_ws + ((size_t)bh * NQ + qr0 + cc) * DK + 8 * gg;
  const bf16x8 aq0 = *(const bf16x8*)qp;
  const bf16x8 aq1 = *(const bf16x8*)(qp + 32);
  const u16* fwrow = fw + ((size_t)b * NQ + qr0 + cc) * NK;
  const f32x4 Z4 = {0.f, 0.f, 0.f, 0.f};
  const int sr = tid >> 3, sc = 8 * (tid & 7);

  // ---- loop1: denominators ----
  float sum = 0.f;
  for (int kc = 0; kc < NK; kc += 128) {
#pragma unroll
    for (int i = 0; i < 4; i++)
      *(bf16x8*)&Ks[i * 32 + sr][sc] =
          *(const bf16x8*)(k_ws + ((size_t)bh * NK + kc + i * 32 + sr) * DK + sc);
    __syncthreads();
#pragma unroll
    for (int n = 0; n < 8; n++) {
      const bf16x8 k0 = *(const bf16x8*)&Ks[n * 16 + cc][8 * gg];
      const bf16x8 k1 = *(const bf16x8*)&Ks[n * 16 + cc][32 + 8 * gg];
      f32x4 acc = Z4;
      acc = MFMA(k0, aq0, acc);
      acc = MFMA(k1, aq1, acc);
      const int k0i = kc + n * 16 + 4 * gg;
      const ushort4 fv = *(const ushort4*)(fwrow + k0i);
      const float e0 = EXP2F(acc[0] * bf2f(fv.x));
      const float e1 = EXP2F(acc[1] * bf2f(fv.y));
      const float e2 = EXP2F(acc[2] * bf2f(fv.z));
      const float e3 = EXP2F(acc[3] * bf2f(fv.w));
      sum += (e0 == e0) ? e0 : 0.f;   // NaN w (masked) -> contributes 0
      sum += (e1 == e1) ? e1 : 0.f;
      sum += (e2 == e2) ? e2 : 0.f;
      sum += (e3 == e3) ? e3 : 0.f;
    }
    __syncthreads();
  }
  sum += __shfl_xor(sum, 16);
  sum += __shfl_xor(sum, 32);         // butterfly: every lane holds the full row sum
  // fold 1/sum into the exponent: p = exp2(acc*fv + lg2r)
  const float lg2r = (sum > 0.f) ? -__log2f(sum) : -__builtin_inff();

  // ---- loop2: normalize, write att, PV ----
  f32x4 o[4];
#pragma unroll
  for (int i = 0; i < 4; i++) o[i] = Z4;
  float* attrow = att_out + (size_t)bh * NQ * NK + (size_t)(qr0 + cc) * NK;

  for (int kc = 0; kc < NK; kc += KC) {
#pragma unroll
    for (int i = 0; i < 2; i++) {
      *(bf16x8*)&Ks[i * 32 + sr][sc] =
          *(const bf16x8*)(k_ws + ((size_t)bh * NK + kc + i * 32 + sr) * DK + sc);
      *(bf16x8*)&Ks[64 + i * 32 + sr][sc] =                 // V tile in rows 64..127
          *(const bf16x8*)(vT_ws + ((size_t)bh * DK + i * 32 + sr) * NK + kc + sc);
    }
    __syncthreads();
    // QK^T swapped: p[q=cc][k=16n+4gg+r]
#pragma unroll
    for (int n = 0; n < 4; n++) {
      const bf16x8 k0 = *(const bf16x8*)&Ks[n * 16 + cc][8 * gg];
      const bf16x8 k1 = *(const bf16x8*)&Ks[n * 16 + cc][32 + 8 * gg];
      f32x4 acc = Z4;
      acc = MFMA(k0, aq0, acc);
      acc = MFMA(k1, aq1, acc);
      const int k0i = kc + n * 16 + 4 * gg;
      const ushort4 fv = *(const ushort4*)(fwrow + k0i);
      const float e0 = EXP2F(fmaf(acc[0], bf2f(fv.x), lg2r));
      const float e1 = EXP2F(fmaf(acc[1], bf2f(fv.y), lg2r));
      const float e2 = EXP2F(fmaf(acc[2], bf2f(fv.z), lg2r));
      const float e3 = EXP2F(fmaf(acc[3], bf2f(fv.w), lg2r));
      f32x4 pv;
      pv.x = (e0 == e0) ? e0 : 0.f;
      pv.y = (e1 == e1) ? e1 : 0.f;
      pv.z = (e2 == e2) ? e2 : 0.f;
      pv.w = (e3 == e3) ? e3 : 0.f;
      __builtin_nontemporal_store(pv, (f32x4*)(attrow + k0i));
      ushort4 pk;
      pk.x = f2bf(pv.x); pk.y = f2bf(pv.y); pk.z = f2bf(pv.z); pk.w = f2bf(pv.w);
      *(ushort4*)&Ps[wid][cc][n * 16 + 4 * gg] = pk;  // per-wave buffer: no barrier needed
    }
    // PV: O[16q x 64d] += P[16q x 64k] * V[64k x 64d]
    const bf16x8 pa0 = *(const bf16x8*)&Ps[wid][cc][8 * gg];
    const bf16x8 pa1 = *(const bf16x8*)&Ps[wid][cc][32 + 8 * gg];
#pragma unroll
    for (int nd = 0; nd < 4; nd++) {
      const bf16x8 vb0 = *(const bf16x8*)&Ks[64 + nd * 16 + cc][8 * gg];
      const bf16x8 vb1 = *(const bf16x8*)&Ks[64 + nd * 16 + cc][32 + 8 * gg];
      o[nd] = MFMA(pa0, vb0, o[nd]);
      o[nd] = MFMA(pa1, vb1, o[nd]);
    }
    __syncthreads();
  }
  // PV C-layout: O[q=4gg+r][d=nd*16+cc]
#pragma unroll
  for (int nd = 0; nd < 4; nd++)
#pragma unroll
    for (int r = 0; r < 4; r++)
      ctxb[((size_t)b * NQ + qr0 + 4 * gg + r) * DM + hh * 64 + nd * 16 + cc] = f2bf(o[nd][r]);
}

// ---------------- K3: out_final = ctx @ Wo^T + bo (bf16 ctx, fp32 Wo in-stage) --------
__global__ __launch_bounds__(256) void k_oproj(
    const u16* __restrict__ ctxb, const float* __restrict__ wo,
    const float* __restrict__ bo, float* __restrict__ outp) {
  __shared__ u16 As[2 * 4096];
  __shared__ u16 Bs[2 * 4096];
  const int bid = blockIdx.x;
  const int swz = ((bid & 7) << 5) + (bid >> 3);
  const int tm = (swz & 31) * 128;
  const int tn = (swz >> 5) * 128;
  f32x4 acc[4][4];
  gemm_core<false, true>(ctxb, wo, tm, tn, As, Bs, acc);
  const int lane = threadIdx.x & 63;
  const int wid = threadIdx.x >> 6;
  const int wm = (wid >> 1) * 64, wn = (wid & 1) * 64;
  const int cc = lane & 15, gg = lane >> 4;
#pragma unroll
  for (int mi = 0; mi < 4; mi++) {
    const int rl = tm + wm + mi * 16 + 4 * gg;
#pragma unroll
    for (int ni = 0; ni < 4; ni++) {
      const int col = tn + wn + ni * 16 + cc;
      const float bs = bo[col];
      f32x4 a = acc[mi][ni];
#pragma unroll
      for (int r = 0; r < 4; r++) outp[(size_t)(rl + r) * DM + col] = a[r] + bs;
    }
  }
}

extern "C" void kernel_launch(void* const* d_in, const int* in_sizes, int n_in,
                              void* d_out, int out_size, void* d_ws, size_t ws_size,
                              hipStream_t stream) {
  (void)in_sizes; (void)n_in; (void)out_size; (void)ws_size;
  const float* queries = (const float*)d_in[0];
  const float* keys    = (const float*)d_in[1];
  const float* values  = (const float*)d_in[2];
  const float* qmask   = (const float*)d_in[3];
  const float* kmask   = (const float*)d_in[4];
  const int*   amask   = (const int*)d_in[5];   // bool -> int32 on device
  const float* attw    = (const float*)d_in[6];
  const float* Wq = (const float*)d_in[7];
  const float* Wk = (const float*)d_in[8];
  const float* Wv = (const float*)d_in[9];
  const float* Wo = (const float*)d_in[10];
  const float* bq = (const float*)d_in[11];
  const float* bk = (const float*)d_in[12];
  const float* bv = (const float*)d_in[13];
  const float* bo = (const float*)d_in[14];

  float* outf = (float*)d_out;
  float* att_out = outf + (size_t)4194304;

  // persistent scratch in d_ws: 50.3 MiB
  char* p = (char*)d_ws;
  u16* q_ws  = (u16*)p; p += (size_t)4194304 * 2;
  u16* k_ws  = (u16*)p; p += (size_t)4194304 * 2;
  u16* vT_ws = (u16*)p; p += (size_t)4194304 * 2;
  u16* ctxb  = (u16*)p; p += (size_t)4194304 * 2;
  u16* fw    = (u16*)p; p += (size_t)8388608 * 2;  // fused mask+weight (pre-scaled by EXPC)

  k_proj<<<dim3(1792, 1, 1), 256, 0, stream>>>(queries, keys, values, Wq, Wk, Wv,
                                               bq, bk, bv, qmask, kmask,
                                               q_ws, k_ws, vT_ws, attw, amask, fw);
  k_attn<<<dim3(32, 32, 1), 256, 0, stream>>>(q_ws, k_ws, vT_ws, fw, att_out, ctxb);
  k_oproj<<<dim3(256, 1, 1), 256, 0, stream>>>(ctxb, Wo, bo, outf);
}

// Round 15
// 331.596 us; speedup vs baseline: 1.4598x; 1.0054x over previous
//
#include <hip/hip_runtime.h>

#define B2 2
#define NQ 2048
#define NK 2048
#define DM 1024
#define NH 16
#define DK 64
#define KC 64

typedef unsigned short u16;
typedef __attribute__((ext_vector_type(8))) short bf16x8;
typedef __attribute__((ext_vector_type(4))) float f32x4;

__device__ __forceinline__ u16 f2bf(float f) {
  unsigned u = __float_as_uint(f);
  u += 0x7FFFu + ((u >> 16) & 1u);
  return (u16)(u >> 16);
}
__device__ __forceinline__ float bf2f(u16 u) {
  return __uint_as_float(((unsigned)u) << 16);
}
// load 8 fp32, round to bf16x8
__device__ __forceinline__ bf16x8 ld8f(const float* __restrict__ p) {
  const float4 a = *(const float4*)p;
  const float4 b = *(const float4*)(p + 4);
  bf16x8 v;
  v[0] = (short)f2bf(a.x); v[1] = (short)f2bf(a.y);
  v[2] = (short)f2bf(a.z); v[3] = (short)f2bf(a.w);
  v[4] = (short)f2bf(b.x); v[5] = (short)f2bf(b.y);
  v[6] = (short)f2bf(b.z); v[7] = (short)f2bf(b.w);
  return v;
}

#if __has_builtin(__builtin_amdgcn_exp2f)
#define EXP2F(x) __builtin_amdgcn_exp2f(x)
#else
#define EXP2F(x) exp2f(x)
#endif

#define MFMA(a, b, c) __builtin_amdgcn_mfma_f32_16x16x32_bf16(a, b, c, 0, 0, 0)

// LDS-only barrier: orders ds_write->ds_read across waves WITHOUT draining vmcnt
// (the nontemporal att stores keep retiring asynchronously across K-chunks)
#define LDS_BARRIER()                                        \
  do {                                                       \
    asm volatile("s_waitcnt lgkmcnt(0)" ::: "memory");       \
    __builtin_amdgcn_s_barrier();                            \
  } while (0)

// exp(x*wgt/8) = exp2(x * (wgt*log2(e)/8)); the /8*log2e factor is FOLDED INTO fw
#define EXPC 0.18033688011112043f

// ------- shared 128x128 GEMM core: Y = A[M,1024] * W[N,1024]^T, fp32/bf16 sources -----
template <bool AF32, bool WF32>
__device__ __forceinline__ void gemm_core(
    const void* __restrict__ Ap, const void* __restrict__ Wp,
    int tm, int tn, u16* As, u16* Bs, f32x4 acc[4][4]) {
  const int tid = threadIdx.x;
  const int lane = tid & 63;
  const int wid = tid >> 6;
  const int wm = (wid >> 1) * 64, wn = (wid & 1) * 64;
  const int cc = lane & 15, gg = lane >> 4;
  const int srow = tid >> 2, scol = 8 * (tid & 3);
  const size_t ra0 = (size_t)(tm + srow) * DM + scol;
  const size_t ra1 = (size_t)(tm + 64 + srow) * DM + scol;
  const size_t rb0 = (size_t)(tn + srow) * DM + scol;
  const size_t rb1 = (size_t)(tn + 64 + srow) * DM + scol;
  const float* Af = (const float*)Ap; const u16* Ab = (const u16*)Ap;
  const float* Wf = (const float*)Wp; const u16* Wb = (const u16*)Wp;
  const f32x4 Z4 = {0.f, 0.f, 0.f, 0.f};
#pragma unroll
  for (int i = 0; i < 4; i++)
#pragma unroll
    for (int j = 0; j < 4; j++) acc[i][j] = Z4;

#define LD_A(off) (AF32 ? ld8f(Af + (off)) : *(const bf16x8*)(Ab + (off)))
#define LD_W(off) (WF32 ? ld8f(Wf + (off)) : *(const bf16x8*)(Wb + (off)))
  *(bf16x8*)&As[tid * 8]        = LD_A(ra0);
  *(bf16x8*)&As[2048 + tid * 8] = LD_A(ra1);
  *(bf16x8*)&Bs[tid * 8]        = LD_W(rb0);
  *(bf16x8*)&Bs[2048 + tid * 8] = LD_W(rb1);

  int buf = 0;
  for (int kk = 0; kk < DM; kk += 32) {
    __syncthreads();
    const int o = buf * 4096;
    bf16x8 af[4], bv[4];
#pragma unroll
    for (int i = 0; i < 4; i++) af[i] = *(const bf16x8*)&As[o + (wm + i * 16 + cc) * 32 + 8 * gg];
#pragma unroll
    for (int i = 0; i < 4; i++) bv[i] = *(const bf16x8*)&Bs[o + (wn + i * 16 + cc) * 32 + 8 * gg];
    if (kk + 32 < DM) {
      const int p = (buf ^ 1) * 4096;
      *(bf16x8*)&As[p + tid * 8]        = LD_A(ra0 + kk + 32);
      *(bf16x8*)&As[p + 2048 + tid * 8] = LD_A(ra1 + kk + 32);
      *(bf16x8*)&Bs[p + tid * 8]        = LD_W(rb0 + kk + 32);
      *(bf16x8*)&Bs[p + 2048 + tid * 8] = LD_W(rb1 + kk + 32);
    }
#pragma unroll
    for (int mi = 0; mi < 4; mi++)
#pragma unroll
      for (int ni = 0; ni < 4; ni++) acc[mi][ni] = MFMA(af[mi], bv[ni], acc[mi][ni]);
    buf ^= 1;
  }
#undef LD_A
#undef LD_W
}

// ---------------- K1: QKV projections + fw conversion (blocks >= 768) ------------------
__global__ __launch_bounds__(256) void k_proj(
    const float* __restrict__ xq, const float* __restrict__ xk, const float* __restrict__ xv,
    const float* __restrict__ wq, const float* __restrict__ wk, const float* __restrict__ wv,
    const float* __restrict__ bq, const float* __restrict__ bk, const float* __restrict__ bv,
    const float* __restrict__ qmask, const float* __restrict__ kmask,
    u16* __restrict__ q_ws, u16* __restrict__ k_ws, u16* __restrict__ vT_ws,
    const float* __restrict__ attw, const int* __restrict__ amask, u16* __restrict__ fwo) {
  const int bid = blockIdx.x;
  if (bid >= 768) {  // fw = amask ? NaN : bf16(attw*EXPC) — overlaps the GEMM blocks
    for (int i = ((bid - 768) * 256 + threadIdx.x) * 8; i < NQ * NK * B2;
         i += 1024 * 256 * 8) {
#pragma unroll
      for (int hh = 0; hh < 2; hh++) {
        const float4 w = *(const float4*)(attw + i + 4 * hh);
        const int4 m = *(const int4*)(amask + i + 4 * hh);
        ushort4 o;
        o.x = m.x ? 0x7FC0 : f2bf(w.x * EXPC);
        o.y = m.y ? 0x7FC0 : f2bf(w.y * EXPC);
        o.z = m.z ? 0x7FC0 : f2bf(w.z * EXPC);
        o.w = m.w ? 0x7FC0 : f2bf(w.w * EXPC);
        *(ushort4*)(fwo + i + 4 * hh) = o;
      }
    }
    return;
  }
  __shared__ u16 As[2 * 4096];
  __shared__ u16 Bs[2 * 4096];
  // bijective XCD swizzle: 768 = 8 x 96
  const int swz = (bid & 7) * 96 + (bid >> 3);
  const int tm = (swz & 31) * 128;
  const int yz = swz >> 5;               // 0..23
  const int tn = (yz & 7) * 128;
  const int z = yz >> 3;                 // 0..2
  const float* A = (z == 0) ? xq : (z == 1) ? xk : xv;
  const float* Wm = (z == 0) ? wq : (z == 1) ? wk : wv;
  const float* bias = (z == 0) ? bq : (z == 1) ? bk : bv;
  const float* rmask = (z == 0) ? qmask : kmask;
  f32x4 acc[4][4];
  gemm_core<true, true>(A, Wm, tm, tn, As, Bs, acc);

  const int lane = threadIdx.x & 63;
  const int wid = threadIdx.x >> 6;
  const int wm = (wid >> 1) * 64, wn = (wid & 1) * 64;
  const int cc = lane & 15, gg = lane >> 4;
  const int b = tm >> 11;
  const int tok0 = tm & 2047;
#pragma unroll
  for (int mi = 0; mi < 4; mi++) {
    const int rl = wm + mi * 16 + 4 * gg;
    float rm[4];
#pragma unroll
    for (int r = 0; r < 4; r++) rm[r] = rmask[b * NQ + tok0 + rl + r];
#pragma unroll
    for (int ni = 0; ni < 4; ni++) {
      const int col = tn + wn + ni * 16 + cc;
      const int h = col >> 6, d = col & 63;
      const float bs = bias[col];
      f32x4 a = acc[mi][ni];
      if (z <= 1) {
        u16* dst = ((z == 0) ? q_ws : k_ws) +
                   ((size_t)(b * NH + h) * NQ + tok0 + rl) * DK + d;
#pragma unroll
        for (int r = 0; r < 4; r++) dst[(size_t)r * DK] = f2bf((a[r] + bs) * rm[r]);
      } else {
        ushort4 pk;
        pk.x = f2bf((a[0] + bs) * rm[0]);
        pk.y = f2bf((a[1] + bs) * rm[1]);
        pk.z = f2bf((a[2] + bs) * rm[2]);
        pk.w = f2bf((a[3] + bs) * rm[3]);
        *(ushort4*)(vT_ws + ((size_t)(b * NH + h) * DK + d) * NK + tok0 + rl) = pk;
      }
    }
  }
}

// ---------------- K2: merged softmax-sum + att write + PV (R11 structure) -------------
// loop2 barriers are LDS-only (lgkmcnt) so nontemporal att stores never drain-stall
__global__ __launch_bounds__(256) void k_attn(
    const u16* __restrict__ q_ws, const u16* __restrict__ k_ws, const u16* __restrict__ vT_ws,
    const u16* __restrict__ fw, float* __restrict__ att_out, u16* __restrict__ ctxb) {
  __shared__ u16 Ks[128][72];         // loop1: 128 K rows; loop2: K rows 0..63, V rows 64..127
  __shared__ u16 Ps[4][16][72];
  const int bh = blockIdx.y;
  const int b = bh >> 4, hh = bh & 15;
  const int qb = blockIdx.x * 64;
  const int tid = threadIdx.x, lane = tid & 63, wid = tid >> 6;
  const int cc = lane & 15, gg = lane >> 4;
  const int qr0 = qb + wid * 16;
  const u16* qp = q_ws + ((size_t)bh * NQ + qr0 + cc) * DK + 8 * gg;
  const bf16x8 aq0 = *(const bf16x8*)qp;
  const bf16x8 aq1 = *(const bf16x8*)(qp + 32);
  const u16* fwrow = fw + ((size_t)b * NQ + qr0 + cc) * NK;
  const f32x4 Z4 = {0.f, 0.f, 0.f, 0.f};
  const int sr = tid >> 3, sc = 8 * (tid & 7);

  // ---- loop1: denominators ----
  float sum = 0.f;
  for (int kc = 0; kc < NK; kc += 128) {
#pragma unroll
    for (int i = 0; i < 4; i++)
      *(bf16x8*)&Ks[i * 32 + sr][sc] =
          *(const bf16x8*)(k_ws + ((size_t)bh * NK + kc + i * 32 + sr) * DK + sc);
    __syncthreads();
#pragma unroll
    for (int n = 0; n < 8; n++) {
      const bf16x8 k0 = *(const bf16x8*)&Ks[n * 16 + cc][8 * gg];
      const bf16x8 k1 = *(const bf16x8*)&Ks[n * 16 + cc][32 + 8 * gg];
      f32x4 acc = Z4;
      acc = MFMA(k0, aq0, acc);
      acc = MFMA(k1, aq1, acc);
      const int k0i = kc + n * 16 + 4 * gg;
      const ushort4 fv = *(const ushort4*)(fwrow + k0i);
      const float e0 = EXP2F(acc[0] * bf2f(fv.x));
      const float e1 = EXP2F(acc[1] * bf2f(fv.y));
      const float e2 = EXP2F(acc[2] * bf2f(fv.z));
      const float e3 = EXP2F(acc[3] * bf2f(fv.w));
      sum += (e0 == e0) ? e0 : 0.f;   // NaN w (masked) -> contributes 0
      sum += (e1 == e1) ? e1 : 0.f;
      sum += (e2 == e2) ? e2 : 0.f;
      sum += (e3 == e3) ? e3 : 0.f;
    }
    __syncthreads();
  }
  sum += __shfl_xor(sum, 16);
  sum += __shfl_xor(sum, 32);         // butterfly: every lane holds the full row sum
  // fold 1/sum into the exponent: p = exp2(acc*fv + lg2r)
  const float lg2r = (sum > 0.f) ? -__log2f(sum) : -__builtin_inff();

  // ---- loop2: normalize, write att, PV ----
  f32x4 o[4];
#pragma unroll
  for (int i = 0; i < 4; i++) o[i] = Z4;
  float* attrow = att_out + (size_t)bh * NQ * NK + (size_t)(qr0 + cc) * NK;

  for (int kc = 0; kc < NK; kc += KC) {
#pragma unroll
    for (int i = 0; i < 2; i++) {
      *(bf16x8*)&Ks[i * 32 + sr][sc] =
          *(const bf16x8*)(k_ws + ((size_t)bh * NK + kc + i * 32 + sr) * DK + sc);
      *(bf16x8*)&Ks[64 + i * 32 + sr][sc] =                 // V tile in rows 64..127
          *(const bf16x8*)(vT_ws + ((size_t)bh * DK + i * 32 + sr) * NK + kc + sc);
    }
    LDS_BARRIER();                     // ds_writes visible; att stores NOT drained
    // QK^T swapped: p[q=cc][k=16n+4gg+r]
#pragma unroll
    for (int n = 0; n < 4; n++) {
      const bf16x8 k0 = *(const bf16x8*)&Ks[n * 16 + cc][8 * gg];
      const bf16x8 k1 = *(const bf16x8*)&Ks[n * 16 + cc][32 + 8 * gg];
      f32x4 acc = Z4;
      acc = MFMA(k0, aq0, acc);
      acc = MFMA(k1, aq1, acc);
      const int k0i = kc + n * 16 + 4 * gg;
      const ushort4 fv = *(const ushort4*)(fwrow + k0i);
      const float e0 = EXP2F(fmaf(acc[0], bf2f(fv.x), lg2r));
      const float e1 = EXP2F(fmaf(acc[1], bf2f(fv.y), lg2r));
      const float e2 = EXP2F(fmaf(acc[2], bf2f(fv.z), lg2r));
      const float e3 = EXP2F(fmaf(acc[3], bf2f(fv.w), lg2r));
      f32x4 pv;
      pv.x = (e0 == e0) ? e0 : 0.f;
      pv.y = (e1 == e1) ? e1 : 0.f;
      pv.z = (e2 == e2) ? e2 : 0.f;
      pv.w = (e3 == e3) ? e3 : 0.f;
      __builtin_nontemporal_store(pv, (f32x4*)(attrow + k0i));
      ushort4 pk;
      pk.x = f2bf(pv.x); pk.y = f2bf(pv.y); pk.z = f2bf(pv.z); pk.w = f2bf(pv.w);
      *(ushort4*)&Ps[wid][cc][n * 16 + 4 * gg] = pk;  // per-wave buffer: no barrier needed
    }
    // PV: O[16q x 64d] += P[16q x 64k] * V[64k x 64d]
    const bf16x8 pa0 = *(const bf16x8*)&Ps[wid][cc][8 * gg];
    const bf16x8 pa1 = *(const bf16x8*)&Ps[wid][cc][32 + 8 * gg];
#pragma unroll
    for (int nd = 0; nd < 4; nd++) {
      const bf16x8 vb0 = *(const bf16x8*)&Ks[64 + nd * 16 + cc][8 * gg];
      const bf16x8 vb1 = *(const bf16x8*)&Ks[64 + nd * 16 + cc][32 + 8 * gg];
      o[nd] = MFMA(pa0, vb0, o[nd]);
      o[nd] = MFMA(pa1, vb1, o[nd]);
    }
    LDS_BARRIER();                     // all reads of Ks done before next stage overwrites
  }
  // PV C-layout: O[q=4gg+r][d=nd*16+cc]
#pragma unroll
  for (int nd = 0; nd < 4; nd++)
#pragma unroll
    for (int r = 0; r < 4; r++)
      ctxb[((size_t)b * NQ + qr0 + 4 * gg + r) * DM + hh * 64 + nd * 16 + cc] = f2bf(o[nd][r]);
}

// ---------------- K3: out_final = ctx @ Wo^T + bo (bf16 ctx, fp32 Wo in-stage) --------
__global__ __launch_bounds__(256) void k_oproj(
    const u16* __restrict__ ctxb, const float* __restrict__ wo,
    const float* __restrict__ bo, float* __restrict__ outp) {
  __shared__ u16 As[2 * 4096];
  __shared__ u16 Bs[2 * 4096];
  const int bid = blockIdx.x;
  const int swz = ((bid & 7) << 5) + (bid >> 3);
  const int tm = (swz & 31) * 128;
  const int tn = (swz >> 5) * 128;
  f32x4 acc[4][4];
  gemm_core<false, true>(ctxb, wo, tm, tn, As, Bs, acc);
  const int lane = threadIdx.x & 63;
  const int wid = threadIdx.x >> 6;
  const int wm = (wid >> 1) * 64, wn = (wid & 1) * 64;
  const int cc = lane & 15, gg = lane >> 4;
#pragma unroll
  for (int mi = 0; mi < 4; mi++) {
    const int rl = tm + wm + mi * 16 + 4 * gg;
#pragma unroll
    for (int ni = 0; ni < 4; ni++) {
      const int col = tn + wn + ni * 16 + cc;
      const float bs = bo[col];
      f32x4 a = acc[mi][ni];
#pragma unroll
      for (int r = 0; r < 4; r++) outp[(size_t)(rl + r) * DM + col] = a[r] + bs;
    }
  }
}

extern "C" void kernel_launch(void* const* d_in, const int* in_sizes, int n_in,
                              void* d_out, int out_size, void* d_ws, size_t ws_size,
                              hipStream_t stream) {
  (void)in_sizes; (void)n_in; (void)out_size; (void)ws_size;
  const float* queries = (const float*)d_in[0];
  const float* keys    = (const float*)d_in[1];
  const float* values  = (const float*)d_in[2];
  const float* qmask   = (const float*)d_in[3];
  const float* kmask   = (const float*)d_in[4];
  const int*   amask   = (const int*)d_in[5];   // bool -> int32 on device
  const float* attw    = (const float*)d_in[6];
  const float* Wq = (const float*)d_in[7];
  const float* Wk = (const float*)d_in[8];
  const float* Wv = (const float*)d_in[9];
  const float* Wo = (const float*)d_in[10];
  const float* bq = (const float*)d_in[11];
  const float* bk = (const float*)d_in[12];
  const float* bv = (const float*)d_in[13];
  const float* bo = (const float*)d_in[14];

  float* outf = (float*)d_out;
  float* att_out = outf + (size_t)4194304;

  // persistent scratch in d_ws: 50.3 MiB
  char* p = (char*)d_ws;
  u16* q_ws  = (u16*)p; p += (size_t)4194304 * 2;
  u16* k_ws  = (u16*)p; p += (size_t)4194304 * 2;
  u16* vT_ws = (u16*)p; p += (size_t)4194304 * 2;
  u16* ctxb  = (u16*)p; p += (size_t)4194304 * 2;
  u16* fw    = (u16*)p; p += (size_t)8388608 * 2;  // fused mask+weight (pre-scaled by EXPC)

  k_proj<<<dim3(1792, 1, 1), 256, 0, stream>>>(queries, keys, values, Wq, Wk, Wv,
                                               bq, bk, bv, qmask, kmask,
                                               q_ws, k_ws, vT_ws, attw, amask, fw);
  k_attn<<<dim3(32, 32, 1), 256, 0, stream>>>(q_ws, k_ws, vT_ws, fw, att_out, ctxb);
  k_oproj<<<dim3(256, 1, 1), 256, 0, stream>>>(ctxb, Wo, bo, outf);
}